// Round 17
// baseline (380.475 us; speedup 1.0000x reference)
//
#include <hip/hip_runtime.h>
#include <hip/hip_bf16.h>
#include <stdint.h>

// CrystalGraphEncoder on MI355X — round 17: bisect after R16 determinism failure.
//  R16 (mm LDS staging + prescale + pk-cvt) passed first validation but FAILED
//  post-timing (5.4e-2, call-history-dependent). Prime structural suspect: mm
//  LDS weight staging. R17 = R15 VERBATIM (which passed all checks) with ONE
//  change: agg decodes {gc,lin} via a single v_cvt_pk_f32_fp8 (was 2 converts).
//  prep / mm0 / mmx / CSR chain / pool / mlp byte-identical to R15.
//
// ws: gr f32 | glpk8 u16 | x bf16 | ebuf | cols | offs | bcnt/bstart/bcur
//     | wprep | pool  (~60 MB)

#define H 64
#define BSHIFT 6
#define BROWS 64

typedef __attribute__((ext_vector_type(8))) short bf16x8;
typedef __attribute__((ext_vector_type(4))) float f32x4;
typedef __attribute__((ext_vector_type(2))) float f32x2;

__device__ __forceinline__ ushort f2bf(float f) {  // RNE
  uint32_t u = __float_as_uint(f);
  u = (u + 0x7fffu + ((u >> 16) & 1u)) >> 16;
  return (ushort)u;
}
// pack: byte0 = fp8(gc), byte1 = fp8(lin)   (OCP e4m3fn, HW convert)
__device__ __forceinline__ ushort pack_gl8(float gc, float lin) {
  return (ushort)(__builtin_amdgcn_cvt_pk_fp8_f32(gc, lin, 0, false) & 0xffff);
}
__device__ __forceinline__ float unpack_lin8(ushort p) {
  return __builtin_amdgcn_cvt_f32_fp8((int)p, 1);
}
__device__ __forceinline__ float sigmoidf_fast(float z) {
  return __builtin_amdgcn_rcpf(1.f + __expf(-z));
}

// ---------- prep: W -> bf16 frag-ready layout; also zeroes bcnt (verbatim R15) ----------
__global__ __launch_bounds__(256) void prep_kernel(
    const float* __restrict__ Wl, const float* __restrict__ Wg,
    bf16x8* __restrict__ wprep, int* __restrict__ bcnt, int nbuck) {
  const int t = blockIdx.x * 256 + threadIdx.x;
  if (t < nbuck) bcnt[t] = 0;
  if (t >= 4608) return;
  const int l = t / 1536;
  const int rem = t - l * 1536;
  const int mat = rem >> 9;
  const int rem2 = rem & 511;
  const int nt = rem2 >> 7;
  const int ks = (rem2 >> 6) & 1;
  const int lane = rem2 & 63;
  const int kg = lane >> 4, l15 = lane & 15;
  const float* src;
  if (mat == 0)      src = Wl + (size_t)l * 4096;
  else if (mat == 1) src = Wg + (size_t)l * 8192;
  else               src = Wg + (size_t)l * 8192 + 4096;
  bf16x8 v;
#pragma unroll
  for (int j = 0; j < 8; j++)
    v[j] = (short)f2bf(src[(size_t)(ks * 32 + kg * 8 + j) * 64 + nt * 16 + l15]);
  wprep[t] = v;
}

// ---------- bucket hist / scan / scatter / csr (verbatim R15) ----------
__global__ __launch_bounds__(256) void bucket_hist_kernel(
    const int* __restrict__ row, int* __restrict__ bcnt, int E, int nbuck) {
  __shared__ int cnt[2048];
  const int tid = threadIdx.x;
  for (int b = tid; b < nbuck; b += 256) cnt[b] = 0;
  __syncthreads();
  for (int e = blockIdx.x * blockDim.x + tid; e < E; e += gridDim.x * blockDim.x)
    atomicAdd(&cnt[row[e] >> BSHIFT], 1);
  __syncthreads();
  for (int b = tid; b < nbuck; b += 256)
    if (cnt[b]) atomicAdd(&bcnt[b], cnt[b]);
}

__global__ __launch_bounds__(1024) void bucket_scan_kernel(
    const int* __restrict__ bcnt, int* __restrict__ bstart,
    int* __restrict__ bcur, int* __restrict__ offs, float* __restrict__ pool,
    int nbuck, int N, int E) {
  __shared__ int sh[1024];
  const int tid = threadIdx.x;
  if (tid < 64) pool[tid] = 0.f;
  const int i0 = 2 * tid, i1 = 2 * tid + 1;
  const int v0 = (i0 < nbuck) ? bcnt[i0] : 0;
  const int v1 = (i1 < nbuck) ? bcnt[i1] : 0;
  const int s = v0 + v1;
  sh[tid] = s;
  __syncthreads();
  for (int off = 1; off < 1024; off <<= 1) {
    const int v = (tid >= off) ? sh[tid - off] : 0;
    __syncthreads();
    sh[tid] += v;
    __syncthreads();
  }
  const int ex = sh[tid] - s;
  if (i0 < nbuck) { bstart[i0] = ex;      bcur[i0] = ex; }
  if (i1 < nbuck) { bstart[i1] = ex + v0; bcur[i1] = ex + v0; }
  if (tid == 0) { bstart[nbuck] = E; offs[N] = E; }
}

#define SCHUNK 4096
__global__ __launch_bounds__(256) void bucket_scatter_kernel(
    const int* __restrict__ row, const int* __restrict__ col,
    int* __restrict__ bcur, uint32_t* __restrict__ ebuf, int E, int nbuck) {
  __shared__ int cnt[2048], base[2048];
  const int tid = threadIdx.x;
  const int start = blockIdx.x * SCHUNK;
  const int end = min(start + SCHUNK, E);
  for (int b = tid; b < nbuck; b += 256) cnt[b] = 0;
  __syncthreads();
  for (int e = start + tid; e < end; e += 256)
    atomicAdd(&cnt[row[e] >> BSHIFT], 1);
  __syncthreads();
  for (int b = tid; b < nbuck; b += 256) {
    if (cnt[b]) base[b] = atomicAdd(&bcur[b], cnt[b]);
    cnt[b] = 0;
  }
  __syncthreads();
  for (int e = start + tid; e < end; e += 256) {
    const int r = row[e];
    const int b = r >> BSHIFT;
    const int pos = base[b] + atomicAdd(&cnt[b], 1);
    ebuf[pos] = ((uint32_t)(r & (BROWS - 1)) << 26) | (uint32_t)col[e];
  }
}

__global__ __launch_bounds__(256) void csr_build_kernel(
    const uint32_t* __restrict__ ebuf, const int* __restrict__ bstart,
    int* __restrict__ offs, int* __restrict__ cols, int N) {
  __shared__ int cnt[BROWS], sc[BROWS];
  const int tid = threadIdx.x;
  const int b = blockIdx.x;
  const int bs = bstart[b], be = bstart[b + 1];
  const int rowbase = b << BSHIFT;
  if (tid < BROWS) cnt[tid] = 0;
  __syncthreads();
  for (int e = bs + tid; e < be; e += 256)
    atomicAdd(&cnt[ebuf[e] >> 26], 1);
  __syncthreads();
  if (tid < BROWS) sc[tid] = cnt[tid];
  __syncthreads();
  for (int off = 1; off < BROWS; off <<= 1) {
    const int v = (tid >= off && tid < BROWS) ? sc[tid - off] : 0;
    __syncthreads();
    if (tid < BROWS) sc[tid] += v;
    __syncthreads();
  }
  if (tid < BROWS) {
    sc[tid] -= cnt[tid];
    cnt[tid] = 0;
    const int r = rowbase + tid;
    if (r < N) offs[r] = bs + sc[tid];
  }
  __syncthreads();
  for (int e = bs + tid; e < be; e += 256) {
    const uint32_t u = ebuf[e];
    const int rl = (int)(u >> 26);
    const int pos = sc[rl] + atomicAdd(&cnt[rl], 1);
    cols[bs + pos] = (int)(u & 0x3FFFFFFu);
  }
}

// ---------- mm0: embed -> layer-0 gr(f32)/glpk8; per-mat loop (verbatim R15) ----------
__global__ __launch_bounds__(256) void node_mm0_mfma(
    const int* __restrict__ an, const float* __restrict__ emb,
    const bf16x8* __restrict__ wp, const float* __restrict__ bl,
    const float* __restrict__ bg, float* __restrict__ gr,
    ushort* __restrict__ glpk8, int N) {
  const int tid = threadIdx.x;
  const int lane = tid & 63, wid = tid >> 6;
  const int l15 = lane & 15, kg = lane >> 4;
  const int mbase = blockIdx.x * 64 + wid * 16;
  const int arow_c = min(mbase + l15, N - 1);

  const int a = an[arow_c];
  const float* src = emb + (size_t)a * H + kg * 8;
  const float4 u0 = *(const float4*)(src);
  const float4 u1 = *(const float4*)(src + 4);
  const float4 u2 = *(const float4*)(src + 32);
  const float4 u3 = *(const float4*)(src + 36);
  bf16x8 a0, a1;
  a0[0] = (short)f2bf(u0.x); a0[1] = (short)f2bf(u0.y);
  a0[2] = (short)f2bf(u0.z); a0[3] = (short)f2bf(u0.w);
  a0[4] = (short)f2bf(u1.x); a0[5] = (short)f2bf(u1.y);
  a0[6] = (short)f2bf(u1.z); a0[7] = (short)f2bf(u1.w);
  a1[0] = (short)f2bf(u2.x); a1[1] = (short)f2bf(u2.y);
  a1[2] = (short)f2bf(u2.z); a1[3] = (short)f2bf(u2.w);
  a1[4] = (short)f2bf(u3.x); a1[5] = (short)f2bf(u3.y);
  a1[6] = (short)f2bf(u3.z); a1[7] = (short)f2bf(u3.w);

  float linv[4][4];
#pragma unroll
  for (int nt = 0; nt < 4; nt++) {
    const float blv = bl[nt * 16 + l15];
    f32x4 acc = (f32x4){blv, blv, blv, blv};
    acc = __builtin_amdgcn_mfma_f32_16x16x32_bf16(a0, wp[(((0 * 4 + nt) * 2 + 0) << 6) + lane], acc, 0, 0, 0);
    acc = __builtin_amdgcn_mfma_f32_16x16x32_bf16(a1, wp[(((0 * 4 + nt) * 2 + 1) << 6) + lane], acc, 0, 0, 0);
#pragma unroll
    for (int r = 0; r < 4; r++) linv[nt][r] = acc[r];
  }
#pragma unroll
  for (int nt = 0; nt < 4; nt++) {
    const float bgv = bg[nt * 16 + l15];
    f32x4 acc = (f32x4){bgv, bgv, bgv, bgv};
    acc = __builtin_amdgcn_mfma_f32_16x16x32_bf16(a0, wp[(((2 * 4 + nt) * 2 + 0) << 6) + lane], acc, 0, 0, 0);
    acc = __builtin_amdgcn_mfma_f32_16x16x32_bf16(a1, wp[(((2 * 4 + nt) * 2 + 1) << 6) + lane], acc, 0, 0, 0);
#pragma unroll
    for (int r = 0; r < 4; r++) {
      const int atom = mbase + kg * 4 + r;
      if (atom < N)
        glpk8[(size_t)atom * H + nt * 16 + l15] = pack_gl8(acc[r], linv[nt][r]);
    }
  }
#pragma unroll
  for (int nt = 0; nt < 4; nt++) {
    f32x4 acc = (f32x4){0.f, 0.f, 0.f, 0.f};
    acc = __builtin_amdgcn_mfma_f32_16x16x32_bf16(a0, wp[(((1 * 4 + nt) * 2 + 0) << 6) + lane], acc, 0, 0, 0);
    acc = __builtin_amdgcn_mfma_f32_16x16x32_bf16(a1, wp[(((1 * 4 + nt) * 2 + 1) << 6) + lane], acc, 0, 0, 0);
#pragma unroll
    for (int r = 0; r < 4; r++) {
      const int atom = mbase + kg * 4 + r;
      if (atom < N) gr[(size_t)atom * H + nt * 16 + l15] = acc[r];
    }
  }
}

// ---------- mmx: x(bf16) -> gr(f32)/glpk8; per-mat loop (verbatim R15) ----------
__global__ __launch_bounds__(256) void node_mmx_mfma(
    const ushort* __restrict__ x, const bf16x8* __restrict__ wp,
    const float* __restrict__ bl, const float* __restrict__ bg,
    float* __restrict__ gr, ushort* __restrict__ glpk8, int N) {
  const int tid = threadIdx.x;
  const int lane = tid & 63, wid = tid >> 6;
  const int l15 = lane & 15, kg = lane >> 4;
  const int mbase = blockIdx.x * 64 + wid * 16;
  const int arow_c = min(mbase + l15, N - 1);
  const ushort* src = x + (size_t)arow_c * H + kg * 8;
  const bf16x8 a0 = *(const bf16x8*)(src);
  const bf16x8 a1 = *(const bf16x8*)(src + 32);

  float linv[4][4];
#pragma unroll
  for (int nt = 0; nt < 4; nt++) {
    const float blv = bl[nt * 16 + l15];
    f32x4 acc = (f32x4){blv, blv, blv, blv};
    acc = __builtin_amdgcn_mfma_f32_16x16x32_bf16(a0, wp[(((0 * 4 + nt) * 2 + 0) << 6) + lane], acc, 0, 0, 0);
    acc = __builtin_amdgcn_mfma_f32_16x16x32_bf16(a1, wp[(((0 * 4 + nt) * 2 + 1) << 6) + lane], acc, 0, 0, 0);
#pragma unroll
    for (int r = 0; r < 4; r++) linv[nt][r] = acc[r];
  }
#pragma unroll
  for (int nt = 0; nt < 4; nt++) {
    const float bgv = bg[nt * 16 + l15];
    f32x4 acc = (f32x4){bgv, bgv, bgv, bgv};
    acc = __builtin_amdgcn_mfma_f32_16x16x32_bf16(a0, wp[(((2 * 4 + nt) * 2 + 0) << 6) + lane], acc, 0, 0, 0);
    acc = __builtin_amdgcn_mfma_f32_16x16x32_bf16(a1, wp[(((2 * 4 + nt) * 2 + 1) << 6) + lane], acc, 0, 0, 0);
#pragma unroll
    for (int r = 0; r < 4; r++) {
      const int atom = mbase + kg * 4 + r;
      if (atom < N)
        glpk8[(size_t)atom * H + nt * 16 + l15] = pack_gl8(acc[r], linv[nt][r]);
    }
  }
#pragma unroll
  for (int nt = 0; nt < 4; nt++) {
    f32x4 acc = (f32x4){0.f, 0.f, 0.f, 0.f};
    acc = __builtin_amdgcn_mfma_f32_16x16x32_bf16(a0, wp[(((1 * 4 + nt) * 2 + 0) << 6) + lane], acc, 0, 0, 0);
    acc = __builtin_amdgcn_mfma_f32_16x16x32_bf16(a1, wp[(((1 * 4 + nt) * 2 + 1) << 6) + lane], acc, 0, 0, 0);
#pragma unroll
    for (int r = 0; r < 4; r++) {
      const int atom = mbase + kg * 4 + r;
      if (atom < N) gr[(size_t)atom * H + nt * 16 + l15] = acc[r];
    }
  }
}

// ---------- aggregate + update: R15 structure; single pk-convert per edge ----------
__global__ __launch_bounds__(256) void agg_kernel(
    const float* __restrict__ gr, const ushort* __restrict__ glpk8,
    const int* __restrict__ offs, const int* __restrict__ cols,
    ushort* __restrict__ x, int N) {
  const int lane = threadIdx.x & 63, w = threadIdx.x >> 6;
  for (int i = blockIdx.x * 4 + w; i < N; i += gridDim.x * 4) {
    const int s = offs[i], e = offs[i + 1];
    const float gri = gr[(size_t)i * H + lane];
    float acc = 0.f;
    for (int cb = s; cb < e; cb += 64) {
      const int nchunk = min(64, e - cb);
      const int myc = (lane < nchunk) ? cols[cb + lane] : 0;
      int j = 0;
      for (; j + 3 < nchunk; j += 4) {
        const int c0 = __shfl(myc, j + 0), c1 = __shfl(myc, j + 1);
        const int c2 = __shfl(myc, j + 2), c3 = __shfl(myc, j + 3);
        const ushort p0 = glpk8[(size_t)c0 * H + lane];
        const ushort p1 = glpk8[(size_t)c1 * H + lane];
        const ushort p2 = glpk8[(size_t)c2 * H + lane];
        const ushort p3 = glpk8[(size_t)c3 * H + lane];
        const f32x2 g0 = __builtin_amdgcn_cvt_pk_f32_fp8((uint32_t)p0, false);
        const f32x2 g1 = __builtin_amdgcn_cvt_pk_f32_fp8((uint32_t)p1, false);
        const f32x2 g2 = __builtin_amdgcn_cvt_pk_f32_fp8((uint32_t)p2, false);
        const f32x2 g3 = __builtin_amdgcn_cvt_pk_f32_fp8((uint32_t)p3, false);
        acc += g0.y * sigmoidf_fast(gri + g0.x);
        acc += g1.y * sigmoidf_fast(gri + g1.x);
        acc += g2.y * sigmoidf_fast(gri + g2.x);
        acc += g3.y * sigmoidf_fast(gri + g3.x);
      }
      for (; j < nchunk; j++) {
        const int c0 = __shfl(myc, j);
        const ushort p0 = glpk8[(size_t)c0 * H + lane];
        const f32x2 g0 = __builtin_amdgcn_cvt_pk_f32_fp8((uint32_t)p0, false);
        acc += g0.y * sigmoidf_fast(gri + g0.x);
      }
    }
    const float li = unpack_lin8(glpk8[(size_t)i * H + lane]);
    x[(size_t)i * H + lane] = f2bf(fmaxf(acc + li, 0.f));
  }
}

// ---------- mean pool (bf16 x), verbatim R15 ----------
__global__ void pool_kernel(const ushort* __restrict__ x,
                            float* __restrict__ pool, int N) {
  __shared__ float ps[4][64];
  const int tid = threadIdx.x, c = tid & 63, wid = tid >> 6;
  float s = 0.f;
  for (int i = blockIdx.x * 4 + wid; i < N; i += gridDim.x * 4)
    s += __uint_as_float(((uint32_t)x[(size_t)i * H + c]) << 16);
  ps[wid][c] = s;
  __syncthreads();
  if (tid < 64) {
    const float t = ps[0][tid] + ps[1][tid] + ps[2][tid] + ps[3][tid];
    atomicAdd(&pool[tid], t);
  }
}

// ---------- final MLP (verbatim R15) ----------
__global__ void mlp_kernel(const float* __restrict__ pool,
                           const float* __restrict__ W1,
                           const float* __restrict__ b1,
                           const float* __restrict__ W2,
                           const float* __restrict__ b2,
                           float* __restrict__ out, float invN) {
  __shared__ float p[64], h[64];
  const int tid = threadIdx.x;
  if (tid < 64) p[tid] = pool[tid] * invN;
  __syncthreads();
  if (tid < 64) {
    float s = b1[tid];
    for (int k = 0; k < 64; k++) s = fmaf(p[k], W1[k * 64 + tid], s);
    h[tid] = fmaxf(s, 0.f);
  }
  __syncthreads();
  float s = b2[tid];
  for (int k = 0; k < 64; k++) s = fmaf(h[k], W2[k * 128 + tid], s);
  out[tid] = s;
}

extern "C" void kernel_launch(void* const* d_in, const int* in_sizes, int n_in,
                              void* d_out, int out_size, void* d_ws,
                              size_t ws_size, hipStream_t stream) {
  const int*   an  = (const int*)d_in[0];
  const int*   ei  = (const int*)d_in[3];
  const float* emb = (const float*)d_in[4];
  const float* Wl  = (const float*)d_in[5];
  const float* bl  = (const float*)d_in[6];
  const float* Wg  = (const float*)d_in[7];
  const float* bg  = (const float*)d_in[8];
  const float* W1  = (const float*)d_in[9];
  const float* b1  = (const float*)d_in[10];
  const float* W2  = (const float*)d_in[11];
  const float* b2  = (const float*)d_in[12];
  float* out = (float*)d_out;

  const int N = in_sizes[0];
  const int E = in_sizes[3] / 2;
  const int* row = ei;
  const int* col = ei + E;
  const int nbuck = (N + BROWS - 1) >> BSHIFT;

  const size_t NH = (size_t)N * H;
  char* ws = (char*)d_ws;
  float*  gr    = (float*)(ws);                     // f32 [N][64]
  ushort* glpk8 = (ushort*)(ws + NH * 4);           // u16 [N][64] (fp8 gc|lin)
  ushort* x     = (ushort*)(ws + NH * 4 + NH * 2);  // bf16 [N][64]
  char* p = ws + NH * 4 + NH * 2 + NH * 2;
  uint32_t* ebuf   = (uint32_t*)p; p += (size_t)E * 4;
  int*      cols   = (int*)p;      p += (size_t)E * 4;
  int*      offs   = (int*)p;      p += ((size_t)N + 1) * 4;
  int*      bcnt   = (int*)p;      p += 8192;
  int*      bstart = (int*)p;      p += 8196;
  int*      bcur   = (int*)p;      p += 8192;
  bf16x8*   wprep  = (bf16x8*)p;   p += 4608 * 16;
  float*    pool   = (float*)p;
  // total ≈ 25.6 + 12.8 + 12.8 + 4 + 4 + 0.4 MB + ~100KB ≈ 60 MB

  prep_kernel<<<18, 256, 0, stream>>>(Wl, Wg, wprep, bcnt, nbuck);

  bucket_hist_kernel<<<1024, 256, 0, stream>>>(row, bcnt, E, nbuck);
  bucket_scan_kernel<<<1, 1024, 0, stream>>>(bcnt, bstart, bcur, offs, pool,
                                             nbuck, N, E);
  bucket_scatter_kernel<<<(E + SCHUNK - 1) / SCHUNK, 256, 0, stream>>>(
      row, col, bcur, ebuf, E, nbuck);
  csr_build_kernel<<<nbuck, 256, 0, stream>>>(ebuf, bstart, offs, cols, N);

  const int mmGrid = (N + 63) / 64;
  const int aggGrid = (N + 3) / 4;

  node_mm0_mfma<<<mmGrid, 256, 0, stream>>>(an, emb, wprep, bl, bg, gr, glpk8, N);
  for (int l = 0; l < 3; l++) {
    agg_kernel<<<aggGrid, 256, 0, stream>>>(gr, glpk8, offs, cols, x, N);
    if (l < 2)
      node_mmx_mfma<<<mmGrid, 256, 0, stream>>>(
          x, wprep + (size_t)(l + 1) * 1536, bl + (size_t)(l + 1) * H,
          bg + (size_t)(l + 1) * H, gr, glpk8, N);
  }

  pool_kernel<<<1024, 256, 0, stream>>>(x, pool, N);
  mlp_kernel<<<1, 128, 0, stream>>>(pool, W1, b1, W2, b2, out, 1.0f / (float)N);
}